// Round 1
// baseline (139.708 us; speedup 1.0000x reference)
//
#include <hip/hip_runtime.h>
#include <hip/hip_bf16.h>

#define D 512
#define NWAY 64
#define KSHOT 16
#define NQ 8192
#define NROWS (NQ + NWAY)   // 8256 embedding rows (queries + class means)

typedef __bf16 bf16_t;
typedef __bf16 bf16x4_t __attribute__((ext_vector_type(4)));
typedef __bf16 bf16x8_t __attribute__((ext_vector_type(8)));
typedef float  f32x4    __attribute__((ext_vector_type(4)));

// ---------------------------------------------------------------- K1
// class means of support -> cmean[64][512] (fp32)
__global__ void k_cmean(const float* __restrict__ sup, float* __restrict__ cmean)
{
    const int c = blockIdx.x;
    for (int d = threadIdx.x; d < D; d += blockDim.x) {
        float s = 0.f;
#pragma unroll
        for (int j = 0; j < KSHOT; ++j) s += sup[(size_t)(c * KSHOT + j) * D + d];
        cmean[(size_t)c * D + d] = s * (1.0f / KSHOT);
    }
}

// ---------------------------------------------------------------- K2
// E[8256][512] (bf16) = [query; cmean] @ W^T + b   via 16x16x32 bf16 MFMA.
// BM=BN=128, BK=32; fp32->bf16 conversion fused into LDS staging.
// LDS tiles padded to stride 40 elems (80B = 20 banks -> 2-way max, free).
__global__ __launch_bounds__(256) void k_emb_gemm(
    const float* __restrict__ query, const float* __restrict__ cmean,
    const float* __restrict__ W,     const float* __restrict__ bias,
    bf16_t* __restrict__ E)
{
    __shared__ bf16_t As[128 * 40];
    __shared__ bf16_t Bs[128 * 40];

    const int m0 = blockIdx.x * 128;
    const int n0 = blockIdx.y * 128;
    const int tid = threadIdx.x;

    // staging coords: 8 threads x float4 cover 32 cols; 32 rows/pass, 4 passes
    const int sr = tid >> 3;          // 0..31
    const int sc = (tid & 7) * 4;     // 0,4,...,28  (fp32 col)
    const float* asrc[4];
    const float* bsrc[4];
#pragma unroll
    for (int p = 0; p < 4; ++p) {
        int rg = m0 + p * 32 + sr;
        if (rg < NQ)         asrc[p] = query + (size_t)rg * D + sc;
        else if (rg < NROWS) asrc[p] = cmean + (size_t)(rg - NQ) * D + sc;
        else                 asrc[p] = nullptr;   // zero-fill tail rows
        bsrc[p] = W + (size_t)(n0 + p * 32 + sr) * D + sc;
    }

    // wave layout: 4 waves in 2x2, each computes 64x64 (4x4 tiles of 16x16)
    const int l    = tid & 63;
    const int w    = tid >> 6;
    const int wm   = w & 1;
    const int wn   = w >> 1;
    const int r15  = l & 15;
    const int quad = l >> 4;

    const bf16_t* Abase = As + (wm * 64 + r15) * 40 + quad * 8;
    const bf16_t* Bbase = Bs + (wn * 64 + r15) * 40 + quad * 8;

    f32x4 acc[4][4];
#pragma unroll
    for (int i = 0; i < 4; ++i)
#pragma unroll
        for (int j = 0; j < 4; ++j) acc[i][j] = (f32x4){0.f, 0.f, 0.f, 0.f};

    for (int kt = 0; kt < D / 32; ++kt) {
        // ---- stage (fp32 load -> bf16 cvt -> LDS) ----
#pragma unroll
        for (int p = 0; p < 4; ++p) {
            float4 av = asrc[p] ? *(const float4*)(asrc[p] + kt * 32)
                                : make_float4(0.f, 0.f, 0.f, 0.f);
            float4 bv = *(const float4*)(bsrc[p] + kt * 32);
            bf16x4_t ah = { (bf16_t)av.x, (bf16_t)av.y, (bf16_t)av.z, (bf16_t)av.w };
            bf16x4_t bh = { (bf16_t)bv.x, (bf16_t)bv.y, (bf16_t)bv.z, (bf16_t)bv.w };
            *(bf16x4_t*)(As + (p * 32 + sr) * 40 + sc) = ah;
            *(bf16x4_t*)(Bs + (p * 32 + sr) * 40 + sc) = bh;
        }
        __syncthreads();

        // ---- fragments + MFMA ----
        bf16x8_t af[4], bfr[4];
#pragma unroll
        for (int mt = 0; mt < 4; ++mt) af[mt]  = *(const bf16x8_t*)(Abase + mt * 640);
#pragma unroll
        for (int nt = 0; nt < 4; ++nt) bfr[nt] = *(const bf16x8_t*)(Bbase + nt * 640);
#pragma unroll
        for (int mt = 0; mt < 4; ++mt)
#pragma unroll
            for (int nt = 0; nt < 4; ++nt)
                acc[mt][nt] = __builtin_amdgcn_mfma_f32_16x16x32_bf16(
                    af[mt], bfr[nt], acc[mt][nt], 0, 0, 0);
        __syncthreads();
    }

    // ---- epilogue: + bias, cast bf16, store E ----
#pragma unroll
    for (int nt = 0; nt < 4; ++nt) {
        int ng = n0 + wn * 64 + nt * 16 + r15;
        float bv = bias[ng];
#pragma unroll
        for (int mt = 0; mt < 4; ++mt) {
#pragma unroll
            for (int reg = 0; reg < 4; ++reg) {
                int rg = m0 + wm * 64 + mt * 16 + quad * 4 + reg;
                if (rg < NROWS)
                    E[(size_t)rg * D + ng] = (bf16_t)(acc[mt][nt][reg] + bv);
            }
        }
    }
}

// ---------------------------------------------------------------- K3
// pn[c] = || proto_c ||^2 from the bf16 prototype rows of E
__global__ void k_pnorm(const bf16_t* __restrict__ E, float* __restrict__ pn)
{
    const int c = blockIdx.x;
    const int l = threadIdx.x;  // 64 threads = 1 wave
    bf16x8_t v = *(const bf16x8_t*)(E + (size_t)(NQ + c) * D + l * 8);
    float s = 0.f;
#pragma unroll
    for (int j = 0; j < 8; ++j) { float x = (float)v[j]; s += x * x; }
#pragma unroll
    for (int off = 32; off; off >>= 1) s += __shfl_down(s, off);
    if (l == 0) pn[c] = s;
}

// ---------------------------------------------------------------- K4
// dists[8192][64] = qn + pn - 2 * E_q . P_c   (MFMA, protos staged in LDS)
// Proto LDS stride 264 elems (528B = 132 banks -> 2-way max, free; 16B aligned)
__global__ __launch_bounds__(256) void k_dist(const bf16_t* __restrict__ E,
                                              const float* __restrict__ pn,
                                              float* __restrict__ out)
{
    __shared__ bf16_t Ps[64 * 264];   // 64 protos x 256-k half, padded
    __shared__ float  pns[64];

    const int tid  = threadIdx.x;
    const int l    = tid & 63;
    const int w    = tid >> 6;
    const int r15  = l & 15;
    const int quad = l >> 4;

    if (tid < 64) pns[tid] = pn[tid];

    const int qrow = blockIdx.x * 64 + w * 16 + r15;       // A-frag row
    const bf16_t* arow = E + (size_t)qrow * D + quad * 8;

    f32x4 acc[4];
#pragma unroll
    for (int nt = 0; nt < 4; ++nt) acc[nt] = (f32x4){0.f, 0.f, 0.f, 0.f};
    float qn = 0.f;

    for (int h = 0; h < 2; ++h) {          // two K-halves of 256
        __syncthreads();                   // protect previous half's reads
        // stage protos k in [h*256, h*256+256): 64 rows x 32 chunks of 8
#pragma unroll
        for (int p = 0; p < 8; ++p) {
            int id = p * 256 + tid;        // 0..2047
            int n  = id >> 5;              // 0..63
            int c8 = (id & 31) * 8;        // 0..248
            *(bf16x8_t*)(Ps + n * 264 + c8) =
                *(const bf16x8_t*)(E + (size_t)(NQ + n) * D + h * 256 + c8);
        }
        __syncthreads();

        for (int kt = 0; kt < 8; ++kt) {
            bf16x8_t a = *(const bf16x8_t*)(arow + h * 256 + kt * 32);
#pragma unroll
            for (int j = 0; j < 8; ++j) { float x = (float)a[j]; qn += x * x; }
#pragma unroll
            for (int nt = 0; nt < 4; ++nt) {
                bf16x8_t b = *(const bf16x8_t*)(Ps + (nt * 16 + r15) * 264 +
                                                kt * 32 + quad * 8);
                acc[nt] = __builtin_amdgcn_mfma_f32_16x16x32_bf16(a, b, acc[nt], 0, 0, 0);
            }
        }
    }

    // full qn per row: sum the 4 k-slices held by lanes {r15, r15+16, +32, +48}
    qn += __shfl_xor(qn, 16);
    qn += __shfl_xor(qn, 32);

#pragma unroll
    for (int reg = 0; reg < 4; ++reg) {
        int rowi = quad * 4 + reg;                 // C/D row within 16
        float qnr = __shfl(qn, rowi);              // qn lives in lane rowi
        int rowg = blockIdx.x * 64 + w * 16 + rowi;
#pragma unroll
        for (int nt = 0; nt < 4; ++nt) {
            int col = nt * 16 + r15;               // C/D col = class
            out[(size_t)rowg * NWAY + col] = qnr + pns[col] - 2.0f * acc[nt][reg];
        }
    }
}

// ---------------------------------------------------------------- launch
extern "C" void kernel_launch(void* const* d_in, const int* in_sizes, int n_in,
                              void* d_out, int out_size, void* d_ws, size_t ws_size,
                              hipStream_t stream)
{
    const float* support = (const float*)d_in[0];
    const float* query   = (const float*)d_in[1];
    const float* W       = (const float*)d_in[2];
    const float* bias    = (const float*)d_in[3];
    float* out = (float*)d_out;

    char* ws = (char*)d_ws;
    bf16_t* E    = (bf16_t*)ws;                              // 8256*512*2 = 8,454,144 B
    float*  cmean = (float*)(ws + 8454144);                  // 64*512*4  =   131,072 B
    float*  pn    = (float*)(ws + 8454144 + 131072);         // 64*4 B

    k_cmean<<<NWAY, 256, 0, stream>>>(support, cmean);

    dim3 g((NROWS + 127) / 128, D / 128);                    // 65 x 4
    k_emb_gemm<<<g, 256, 0, stream>>>(query, cmean, W, bias, E);

    k_pnorm<<<NWAY, 64, 0, stream>>>(E, pn);

    k_dist<<<NQ / 64, 256, 0, stream>>>(E, pn, out);
}